// Round 12
// baseline (392.150 us; speedup 1.0000x reference)
//
#include <hip/hip_runtime.h>
#include <cstdint>

#define N_NODES 100000
#define BQ      20000
#define KN      32
#define NEGV    -1000000.0f

typedef float    f32x4 __attribute__((ext_vector_type(4)));
typedef _Float16 h16x4 __attribute__((ext_vector_type(4)));
typedef _Float16 h16x8 __attribute__((ext_vector_type(8)));

__device__ __forceinline__ int imin(int a, int b) { return a < b ? a : b; }

// ---------------------------------------------------------------------------
// Kernel 1: proj = leaky_relu(word_vec @ W1^T), fused with wv->f16 conversion.
// No LDS, no barriers: each wave loads A (wv, fp32) and B (W1, fp32) fragments
// directly from global (16B granules), converts in-register, MFMAs. 8 unrolled
// ks-steps x (8 A-loads + 8 B-loads, all independent) give deep ILP.
// Block = 64 rows x 256 cols; wave w owns cols [64w, 64w+64).
// Side outputs into ws16 ([N,512] f16, 1KB/node): wv16 half written from the
// A-fragments (wave w writes its mi==w rows), pj16 half from the epilogue.
// fp32 out stores are non-temporal (write-once, never re-read before check).
// ---------------------------------------------------------------------------
__global__ __launch_bounds__(256) void proj_fused(const float* __restrict__ wv,
                                                  const float* __restrict__ W,
                                                  float* __restrict__ out,
                                                  _Float16* __restrict__ ws16) {
    const int m0 = blockIdx.x * 64;
    const int t = threadIdx.x;
    const int lane = t & 63;
    const int w = t >> 6;
    const int wn = w * 64;
    const int rg = lane & 15;   // row/col-in-16 within fragment
    const int g = lane >> 4;    // k-subgroup (8 f16 each)

    f32x4 acc[4][4];
#pragma unroll
    for (int i = 0; i < 4; ++i)
#pragma unroll
        for (int j = 0; j < 4; ++j) acc[i][j] = f32x4{0.f, 0.f, 0.f, 0.f};

#pragma unroll
    for (int ks = 0; ks < 8; ++ks) {
        const int kc = ks * 32 + g * 8;  // k-column base (f32/f16 index)

        // B fragments: W1[nrow][kc..kc+8) -> f16
        h16x8 bq[4];
#pragma unroll
        for (int ni = 0; ni < 4; ++ni) {
            const float* p = &W[(size_t)(wn + ni * 16 + rg) * 256 + kc];
            f32x4 b0 = *(const f32x4*)p;
            f32x4 b1 = *(const f32x4*)(p + 4);
            bq[ni] = h16x8{(_Float16)b0[0], (_Float16)b0[1], (_Float16)b0[2],
                           (_Float16)b0[3], (_Float16)b1[0], (_Float16)b1[1],
                           (_Float16)b1[2], (_Float16)b1[3]};
        }

        // A fragments: wv[r][kc..kc+8) -> f16 (+ wv16 side-write for mi==w)
        h16x8 af[4];
#pragma unroll
        for (int mi = 0; mi < 4; ++mi) {
            const int r = imin(m0 + mi * 16 + rg, N_NODES - 1);
            const float* p = &wv[(size_t)r * 256 + kc];
            f32x4 a0 = *(const f32x4*)p;
            f32x4 a1 = *(const f32x4*)(p + 4);
            af[mi] = h16x8{(_Float16)a0[0], (_Float16)a0[1], (_Float16)a0[2],
                           (_Float16)a0[3], (_Float16)a1[0], (_Float16)a1[1],
                           (_Float16)a1[2], (_Float16)a1[3]};
            // wave w owns the wv16 write for its mi==w rows (static index)
            if (mi == w) {
                const int rw = m0 + mi * 16 + rg;
                if (rw < N_NODES) *(h16x8*)&ws16[(size_t)rw * 512 + kc] = af[mi];
            }
        }

#pragma unroll
        for (int mi = 0; mi < 4; ++mi)
#pragma unroll
            for (int ni = 0; ni < 4; ++ni)
                acc[mi][ni] = __builtin_amdgcn_mfma_f32_16x16x32_f16(af[mi], bq[ni],
                                                                     acc[mi][ni], 0, 0, 0);
    }

    // ---- epilogue: leaky_relu + fp32 out (NT) + f16 pj16 half (cached) ----
    const int cr = g * 4;  // fragment row base
#pragma unroll
    for (int mi = 0; mi < 4; ++mi) {
#pragma unroll
        for (int r = 0; r < 4; ++r) {
            const int grow = m0 + mi * 16 + cr + r;
            if (grow < N_NODES) {
#pragma unroll
                for (int ni = 0; ni < 4; ++ni) {
                    float v = acc[mi][ni][r];
                    v = v > 0.f ? v : 0.2f * v;
                    const int col = wn + ni * 16 + rg;
                    __builtin_nontemporal_store(v, &out[(size_t)grow * 256 + col]);
                    ws16[(size_t)grow * 512 + 256 + col] = (_Float16)v;
                }
            }
        }
    }
}

// ---------------------------------------------------------------------------
// Kernel 2: scores + masked dual softmax + weighted aggregation, fused scatter.
// One block / b; wave w owns neighbors 8w..8w+7. Gathers from interleaved f16
// ws (cached; k and v rows adjacent). aux read + agg store are non-temporal.
// ---------------------------------------------------------------------------
__global__ __launch_bounds__(256) void att_agg16(const _Float16* __restrict__ ws16,
                                                 const float* __restrict__ Waux,
                                                 const float* __restrict__ aux,
                                                 const int* __restrict__ src_idx,
                                                 const int* __restrict__ nidx,
                                                 const int* __restrict__ smask,
                                                 float* __restrict__ out) {
    __shared__ int   nsh[32];
    __shared__ int   msh[32];
    __shared__ float sc[32];
    __shared__ float sa[32];
    __shared__ float wsh[32];
    __shared__ float part[4][64][4];

    const int b = blockIdx.x;
    const int t = threadIdx.x;
    const int lane = t & 63;
    const int w = t >> 6;
    const int src = src_idx[b];

    if (t < 32) {
        nsh[t] = nidx[b * KN + t];
        msh[t] = smask[b * KN + t];
        f32x4 a4 = __builtin_nontemporal_load((const f32x4*)&aux[((size_t)b * KN + t) * 4]);
        const float x = a4[0] * Waux[0] + a4[1] * Waux[1] + a4[2] * Waux[2] + a4[3] * Waux[3];
        sa[t] = 1.f / (1.f + expf(-x));
    }
    const h16x4 qh = *(const h16x4*)&ws16[(size_t)src * 512 + lane * 4];
    const float q0 = (float)qh[0], q1 = (float)qh[1], q2 = (float)qh[2], q3 = (float)qh[3];
    __syncthreads();

    int nk[8];
#pragma unroll
    for (int i = 0; i < 8; ++i) nk[i] = nsh[w * 8 + i];

    // preload 8 k rows + 8 v rows (8B/lane each; k and v adjacent in memory)
    h16x4 k4[8], v4[8];
#pragma unroll
    for (int i = 0; i < 8; ++i)
        k4[i] = *(const h16x4*)&ws16[(size_t)nk[i] * 512 + lane * 4];
#pragma unroll
    for (int i = 0; i < 8; ++i)
        v4[i] = *(const h16x4*)&ws16[(size_t)nk[i] * 512 + 256 + lane * 4];

    // scores: full-wave 256-dim dots
#pragma unroll
    for (int i = 0; i < 8; ++i) {
        float p = q0 * (float)k4[i][0] + q1 * (float)k4[i][1] + q2 * (float)k4[i][2] +
                  q3 * (float)k4[i][3];
#pragma unroll
        for (int o = 32; o > 0; o >>= 1) p += __shfl_xor(p, o);
        if (lane == 0) sc[w * 8 + i] = 5.f * p;
    }
    __syncthreads();

    // masked dual softmax over K=32 (lanes 0..31 of wave 0)
    if (t < 32) {
        const bool mk = (msh[t] == 1);
        const float s1 = mk ? sc[t] : NEGV;
        const float s2 = mk ? sa[t] : NEGV;
        float m1 = s1, m2 = s2;
#pragma unroll
        for (int o = 16; o > 0; o >>= 1) {
            m1 = fmaxf(m1, __shfl_xor(m1, o));
            m2 = fmaxf(m2, __shfl_xor(m2, o));
        }
        const float e1 = expf(s1 - m1), e2 = expf(s2 - m2);
        float z1 = e1, z2 = e2;
#pragma unroll
        for (int o = 16; o > 0; o >>= 1) {
            z1 += __shfl_xor(z1, o);
            z2 += __shfl_xor(z2, o);
        }
        wsh[t] = 0.5f * (e1 / z1 + e2 / z2);
    }
    __syncthreads();

    // weighted partial sum (v4 already in regs)
    f32x4 pacc = f32x4{0.f, 0.f, 0.f, 0.f};
#pragma unroll
    for (int i = 0; i < 8; ++i) {
        const float wk = wsh[w * 8 + i];
#pragma unroll
        for (int j = 0; j < 4; ++j) pacc[j] += wk * (float)v4[i][j];
    }
    *(f32x4*)&part[w][lane][0] = pacc;
    __syncthreads();

    if (w == 0) {
        f32x4 s0 = *(const f32x4*)&part[0][lane][0];
        f32x4 s1 = *(const f32x4*)&part[1][lane][0];
        f32x4 s2 = *(const f32x4*)&part[2][lane][0];
        f32x4 s3 = *(const f32x4*)&part[3][lane][0];
        f32x4 s;
#pragma unroll
        for (int j = 0; j < 4; ++j) s[j] = (s0[j] + s1[j]) + (s2[j] + s3[j]);
        __builtin_nontemporal_store(s, (f32x4*)&out[(size_t)src * 256 + lane * 4]);
    }
}

extern "C" void kernel_launch(void* const* d_in, const int* in_sizes, int n_in,
                              void* d_out, int out_size, void* d_ws, size_t ws_size,
                              hipStream_t stream) {
    const float* wv   = (const float*)d_in[0];  // word_vec [N,256]
    const float* W1   = (const float*)d_in[1];  // [256,256]
    const float* Waux = (const float*)d_in[2];  // [1,4]
    const float* aux  = (const float*)d_in[3];  // [B,K,4]
    const int*   src  = (const int*)d_in[4];    // [B]
    const int*   nidx = (const int*)d_in[5];    // [B,K]
    const int*   smk  = (const int*)d_in[6];    // [B,K]
    float* out = (float*)d_out;                 // [N,256]
    _Float16* ws16 = (_Float16*)d_ws;           // [N,512] interleaved (102.4 MB)

    proj_fused<<<dim3((N_NODES + 63) / 64), dim3(256), 0, stream>>>(wv, W1, out, ws16);
    att_agg16<<<dim3(BQ), dim3(256), 0, stream>>>(ws16, Waux, aux, src, nidx, smk, out);
}

// Round 13
// 327.851 us; speedup vs baseline: 1.1961x; 1.1961x over previous
//
#include <hip/hip_runtime.h>
#include <cstdint>

#define N_NODES 100000
#define BQ      20000
#define KN      32
#define NEGV    -1000000.0f

typedef float    f32x4 __attribute__((ext_vector_type(4)));
typedef _Float16 h16x4 __attribute__((ext_vector_type(4)));
typedef _Float16 h16x8 __attribute__((ext_vector_type(8)));

__device__ __forceinline__ int imin(int a, int b) { return a < b ? a : b; }

#define GLOAD_LDS16(g, l)                                                      \
    __builtin_amdgcn_global_load_lds(                                          \
        (const __attribute__((address_space(1))) unsigned int*)(g),            \
        (__attribute__((address_space(3))) unsigned int*)(l), 16, 0, 0)

// ---------------------------------------------------------------------------
// Kernel 0: fp32 -> f16 conversions.
//  - ws16 [N,512] interleaved: [0,256)=wv16 row (written here), [256,512)=pj16
//    row (written by proj_gemm).
//  - w16 (optional, 128 KB at ws tail): f16 copy of W1 so proj's B-fragments
//    are direct f16 loads with no convert chain.
// ---------------------------------------------------------------------------
__global__ __launch_bounds__(256) void prep_f16(const float* __restrict__ wv,
                                                const float* __restrict__ W,
                                                _Float16* __restrict__ ws16,
                                                _Float16* __restrict__ w16) {
    const int stride = gridDim.x * blockDim.x;
    const int wchunks = (256 * 256) / 8;          // 8192
    const int total = N_NODES * 32 + wchunks;
    for (int i = blockIdx.x * blockDim.x + threadIdx.x; i < total; i += stride) {
        if (i < wchunks) {
            if (w16 != nullptr) {
                const size_t e = (size_t)i * 8;
                f32x4 a = *(const f32x4*)&W[e];
                f32x4 b = *(const f32x4*)&W[e + 4];
                h16x8 h = {(_Float16)a[0], (_Float16)a[1], (_Float16)a[2], (_Float16)a[3],
                           (_Float16)b[0], (_Float16)b[1], (_Float16)b[2], (_Float16)b[3]};
                *(h16x8*)&w16[e] = h;
            }
        } else {
            const size_t e = (size_t)(i - wchunks) * 8;
            const size_t n = e >> 8, c = e & 255;
            f32x4 a = *(const f32x4*)&wv[e];
            f32x4 b = *(const f32x4*)&wv[e + 4];
            h16x8 h = {(_Float16)a[0], (_Float16)a[1], (_Float16)a[2], (_Float16)a[3],
                       (_Float16)b[0], (_Float16)b[1], (_Float16)b[2], (_Float16)b[3]};
            *(h16x8*)&ws16[n * 512 + c] = h;
        }
    }
}

// ---------------------------------------------------------------------------
// Kernel 1: proj = leaky_relu(word_vec @ W1^T) -> out (fp32) + pj16 half of ws.
// BM=64, BN=256, BK=64; 4 waves, wave w owns cols [64w,64w+64).
// A staged from f16 ws via global_load_lds(16B), double-buffered, swizzled
// (structure measured at 101us in round 10). B fragments:
//   WF16=true : direct f16 16B loads from w16 (no cvt; loop-invariant regs)
//   WF16=false: fp32 loads + convert (round-10 fallback)
// ---------------------------------------------------------------------------
template <bool WF16>
__global__ __launch_bounds__(256, 2) void proj_gemm(const _Float16* __restrict__ ws16,
                                                    const float* __restrict__ W,
                                                    const _Float16* __restrict__ w16,
                                                    float* __restrict__ out,
                                                    _Float16* __restrict__ pjdst) {
    __shared__ _Float16 As[2][64 * 64];  // 2 x 8 KiB, row stride 128B, swizzled

    const int m0 = blockIdx.x * 64;
    const int t = threadIdx.x;
    const int lane = t & 63;
    const int w = t >> 6;
    const int wn = w * 64;
    const int rg = lane & 15;
    const int g = lane >> 4;

    // ---- stage(kk=0, buf 0): wave w stages rows w*16 .. w*16+15 ----
    const int chs = ((lane & 7) ^ (lane >> 3)) * 16;  // swizzled source chunk byte
    {
#pragma unroll
        for (int i = 0; i < 2; ++i) {
            const int r0 = w * 16 + i * 8;
            const int grow = imin(m0 + r0 + (lane >> 3), N_NODES - 1);
            const char* gp = (const char*)ws16 + (size_t)grow * 1024 + chs;
            GLOAD_LDS16(gp, (char*)&As[0][0] + r0 * 128);
        }
    }

    // ---- B fragments for this wave's 64 cols (loop-invariant) ----
    h16x8 bq[4][8];
#pragma unroll
    for (int ni = 0; ni < 4; ++ni) {
#pragma unroll
        for (int ks = 0; ks < 8; ++ks) {
            const int nrow = wn + ni * 16 + rg;
            const int kb = ks * 32 + g * 8;
            if constexpr (WF16) {
                bq[ni][ks] = *(const h16x8*)&w16[(size_t)nrow * 256 + kb];
            } else {
                f32x4 v0 = *(const f32x4*)&W[(size_t)nrow * 256 + kb];
                f32x4 v1 = *(const f32x4*)&W[(size_t)nrow * 256 + kb + 4];
                bq[ni][ks] = h16x8{(_Float16)v0[0], (_Float16)v0[1], (_Float16)v0[2],
                                   (_Float16)v0[3], (_Float16)v1[0], (_Float16)v1[1],
                                   (_Float16)v1[2], (_Float16)v1[3]};
            }
        }
    }

    f32x4 acc[4][4];
#pragma unroll
    for (int i = 0; i < 4; ++i)
#pragma unroll
        for (int j = 0; j < 4; ++j) acc[i][j] = f32x4{0.f, 0.f, 0.f, 0.f};

    asm volatile("s_waitcnt vmcnt(0)" ::: "memory");
    __syncthreads();

#pragma unroll
    for (int kk = 0; kk < 4; ++kk) {
        const int cur = kk & 1;
        // prefetch next A K-slice into the other buffer
        if (kk < 3) {
#pragma unroll
            for (int i = 0; i < 2; ++i) {
                const int r0 = w * 16 + i * 8;
                const int grow = imin(m0 + r0 + (lane >> 3), N_NODES - 1);
                const char* gp =
                    (const char*)ws16 + (size_t)grow * 1024 + (kk + 1) * 128 + chs;
                GLOAD_LDS16(gp, (char*)&As[cur ^ 1][0] + r0 * 128);
            }
        }
        // compute on current buffer: 2 sub-steps of K=32
#pragma unroll
        for (int ksl = 0; ksl < 2; ++ksl) {
            const int colb = ksl * 64 + (g * 16);
            h16x8 af[4];
#pragma unroll
            for (int mi = 0; mi < 4; ++mi) {
                const int row = mi * 16 + rg;
                const int byte = row * 128 + (colb ^ ((row & 7) << 4));
                af[mi] = *(const h16x8*)((const char*)&As[cur][0] + byte);
            }
#pragma unroll
            for (int mi = 0; mi < 4; ++mi)
#pragma unroll
                for (int ni = 0; ni < 4; ++ni)
                    acc[mi][ni] = __builtin_amdgcn_mfma_f32_16x16x32_f16(
                        af[mi], bq[ni][kk * 2 + ksl], acc[mi][ni], 0, 0, 0);
        }
        asm volatile("s_waitcnt vmcnt(0)" ::: "memory");
        __syncthreads();
    }

    // ---- epilogue: leaky_relu + fp32 out + f16 pj16 half ----
    const int cr = g * 4;
#pragma unroll
    for (int mi = 0; mi < 4; ++mi) {
#pragma unroll
        for (int r = 0; r < 4; ++r) {
            const int grow = m0 + mi * 16 + cr + r;
            if (grow < N_NODES) {
#pragma unroll
                for (int ni = 0; ni < 4; ++ni) {
                    float v = acc[mi][ni][r];
                    v = v > 0.f ? v : 0.2f * v;
                    const int col = wn + ni * 16 + rg;
                    out[(size_t)grow * 256 + col] = v;
                    pjdst[(size_t)grow * 512 + 256 + col] = (_Float16)v;
                }
            }
        }
    }
}

// ---------------------------------------------------------------------------
// Kernel 2: scores + masked dual softmax + weighted aggregation, fused scatter.
// Exactly the round-9 version measured at 94.4 us. One block / b; wave w owns
// neighbors 8w..8w+7; gathers from interleaved f16 ws (k,v rows adjacent).
// ---------------------------------------------------------------------------
__global__ __launch_bounds__(256) void att_agg16(const _Float16* __restrict__ ws16,
                                                 const float* __restrict__ Waux,
                                                 const float* __restrict__ aux,
                                                 const int* __restrict__ src_idx,
                                                 const int* __restrict__ nidx,
                                                 const int* __restrict__ smask,
                                                 float* __restrict__ out) {
    __shared__ int   nsh[32];
    __shared__ int   msh[32];
    __shared__ float sc[32];
    __shared__ float sa[32];
    __shared__ float wsh[32];
    __shared__ float part[4][64][4];

    const int b = blockIdx.x;
    const int t = threadIdx.x;
    const int lane = t & 63;
    const int w = t >> 6;
    const int src = src_idx[b];

    if (t < 32) {
        nsh[t] = nidx[b * KN + t];
        msh[t] = smask[b * KN + t];
        f32x4 a4 = *(const f32x4*)&aux[((size_t)b * KN + t) * 4];
        const float x = a4[0] * Waux[0] + a4[1] * Waux[1] + a4[2] * Waux[2] + a4[3] * Waux[3];
        sa[t] = 1.f / (1.f + expf(-x));
    }
    const h16x4 qh = *(const h16x4*)&ws16[(size_t)src * 512 + lane * 4];
    const float q0 = (float)qh[0], q1 = (float)qh[1], q2 = (float)qh[2], q3 = (float)qh[3];
    __syncthreads();

    int nk[8];
#pragma unroll
    for (int i = 0; i < 8; ++i) nk[i] = nsh[w * 8 + i];

    // preload 8 k rows + 8 v rows (8B/lane each; k and v adjacent in memory)
    h16x4 k4[8], v4[8];
#pragma unroll
    for (int i = 0; i < 8; ++i)
        k4[i] = *(const h16x4*)&ws16[(size_t)nk[i] * 512 + lane * 4];
#pragma unroll
    for (int i = 0; i < 8; ++i)
        v4[i] = *(const h16x4*)&ws16[(size_t)nk[i] * 512 + 256 + lane * 4];

    // scores: full-wave 256-dim dots
#pragma unroll
    for (int i = 0; i < 8; ++i) {
        float p = q0 * (float)k4[i][0] + q1 * (float)k4[i][1] + q2 * (float)k4[i][2] +
                  q3 * (float)k4[i][3];
#pragma unroll
        for (int o = 32; o > 0; o >>= 1) p += __shfl_xor(p, o);
        if (lane == 0) sc[w * 8 + i] = 5.f * p;
    }
    __syncthreads();

    // masked dual softmax over K=32 (lanes 0..31 of wave 0)
    if (t < 32) {
        const bool mk = (msh[t] == 1);
        const float s1 = mk ? sc[t] : NEGV;
        const float s2 = mk ? sa[t] : NEGV;
        float m1 = s1, m2 = s2;
#pragma unroll
        for (int o = 16; o > 0; o >>= 1) {
            m1 = fmaxf(m1, __shfl_xor(m1, o));
            m2 = fmaxf(m2, __shfl_xor(m2, o));
        }
        const float e1 = expf(s1 - m1), e2 = expf(s2 - m2);
        float z1 = e1, z2 = e2;
#pragma unroll
        for (int o = 16; o > 0; o >>= 1) {
            z1 += __shfl_xor(z1, o);
            z2 += __shfl_xor(z2, o);
        }
        wsh[t] = 0.5f * (e1 / z1 + e2 / z2);
    }
    __syncthreads();

    // weighted partial sum (v4 already in regs)
    f32x4 pacc = f32x4{0.f, 0.f, 0.f, 0.f};
#pragma unroll
    for (int i = 0; i < 8; ++i) {
        const float wk = wsh[w * 8 + i];
#pragma unroll
        for (int j = 0; j < 4; ++j) pacc[j] += wk * (float)v4[i][j];
    }
    *(f32x4*)&part[w][lane][0] = pacc;
    __syncthreads();

    if (w == 0) {
        f32x4 s0 = *(const f32x4*)&part[0][lane][0];
        f32x4 s1 = *(const f32x4*)&part[1][lane][0];
        f32x4 s2 = *(const f32x4*)&part[2][lane][0];
        f32x4 s3 = *(const f32x4*)&part[3][lane][0];
        f32x4 s;
#pragma unroll
        for (int j = 0; j < 4; ++j) s[j] = (s0[j] + s1[j]) + (s2[j] + s3[j]);
        *(f32x4*)&out[(size_t)src * 256 + lane * 4] = s;  // fused scatter
    }
}

extern "C" void kernel_launch(void* const* d_in, const int* in_sizes, int n_in,
                              void* d_out, int out_size, void* d_ws, size_t ws_size,
                              hipStream_t stream) {
    const float* wv   = (const float*)d_in[0];  // word_vec [N,256]
    const float* W1   = (const float*)d_in[1];  // [256,256]
    const float* Waux = (const float*)d_in[2];  // [1,4]
    const float* aux  = (const float*)d_in[3];  // [B,K,4]
    const int*   src  = (const int*)d_in[4];    // [B]
    const int*   nidx = (const int*)d_in[5];    // [B,K]
    const int*   smk  = (const int*)d_in[6];    // [B,K]
    float* out = (float*)d_out;                 // [N,256]

    const size_t nelems = (size_t)N_NODES * 512;          // ws16 elems
    const size_t need_base = nelems * sizeof(_Float16);   // 102.4 MB (proven to fit)
    const size_t need_w = (size_t)256 * 256 * sizeof(_Float16);  // 128 KB

    _Float16* ws16 = (_Float16*)d_ws;
    const bool has_w16 = (ws_size >= need_base + need_w);
    _Float16* w16 = has_w16 ? ws16 + nelems : nullptr;

    prep_f16<<<dim3(8192), dim3(256), 0, stream>>>(wv, W1, ws16, w16);
    if (has_w16) {
        proj_gemm<true><<<dim3((N_NODES + 63) / 64), dim3(256), 0, stream>>>(
            ws16, W1, w16, out, ws16);
    } else {
        proj_gemm<false><<<dim3((N_NODES + 63) / 64), dim3(256), 0, stream>>>(
            ws16, W1, nullptr, out, ws16);
    }
    att_agg16<<<dim3(BQ), dim3(256), 0, stream>>>(ws16, Waux, aux, src, nidx, smk, out);
}